// Round 1
// baseline (403.848 us; speedup 1.0000x reference)
//
#include <hip/hip_runtime.h>

#define SEQ     256
#define FEAT    768
#define WIN     3
#define FILT    6
#define KTOT    (WIN * FEAT)       // 2304
#define WELEMS  (KTOT * FILT)      // 13824 floats = 55296 B
#define NB      8                  // batches per group (all waves together)
#define BLOCK   768                // 12 waves: 3 window-rows x 4 f-quarters
#define NWAVES  12
#define NGROUPS 16                 // per block: half the batches (2 blocks/s)
#define RSTR    49                 // reduction row stride (48 + 1 pad)

// R6: occupancy doubling. Grid 512 = 2 blocks per s (batch halves b<128 /
// b>=128). 2 co-resident 768-thr blocks/CU: LDS 2x60416=118KB<=160KB,
// VGPR 52 <= 85 (6 waves/SIMD cap) -> 24 waves/CU instead of 12. One
// block's barrier+finalizer drain overlaps the other block's FMA stream.
// XCD swizzle preserved: blk and blk+256 share blk&7, so both halves of
// an s-range stay on one XCD; active L2 x-footprint 34 rows x 8 b x 3KB
// x 2 halves = 1.6MB < 4MB, so each row still fetched once per XCD.
// ALL 12 waves process the SAME 8-batch group, splitting K: wave = (w, fq),
// lane owns f = 192*fq+lane (+64j, j<3).
__global__ __launch_bounds__(BLOCK, 6)
void pos_linear_kernel(const float* __restrict__ x,
                       const float* __restrict__ W,
                       const float* __restrict__ bias,
                       float* __restrict__ out) {
    __shared__ float wlds[WELEMS];
    __shared__ float red[2][NWAVES * RSTR];   // parity => 1 barrier/group

    const int blk  = blockIdx.x;
    const int half = blk >> 8;                      // batch half 0/1
    const int sb   = blk & 255;
    const int s    = ((sb & 7) << 5) | (sb >> 3);   // XCD k <- s in [32k,32k+32)
    const int tid  = threadIdx.x;

    // Stage W[s] -> LDS, float4 coalesced (R1-proven layout: row-major k*6+o)
    {
        const float4* src = (const float4*)(W + (size_t)s * WELEMS);
        float4*       dst = (float4*)wlds;
        for (int i = tid; i < WELEMS / 4; i += BLOCK) dst[i] = src[i];
    }

    const int lane = tid & 63;
    const int wave = tid >> 6;           // 0..11
    const int w    = wave >> 2;          // window row 0..2
    const int q    = wave & 3;           // f-quarter 0..3
    const int r    = s - 1 + w;          // input row
    const bool valid = (r >= 0) && (r < SEQ);
    const int  f0   = 192 * q + lane;    // this lane's first feature
    const int  k0   = FEAT * w + f0;     // K index into W
    const float* xrow = valid ? (x + (size_t)r * FEAT + f0) : x;

    // R2-verified halving-tree output mapping: lane<16 holds idx 3*bitrev4+j
    const int gidx = ((lane & 1) << 3) | ((lane & 2) << 1) |
                     ((lane & 4) >> 1) | ((lane & 8) >> 3);

    __syncthreads();

    for (int g = 0; g < NGROUPS; ++g) {
        const int b0 = (half << 7) + (g << 3);   // this block's batch base

        float v[NB * FILT];              // accumulate directly in v[]
        #pragma unroll
        for (int i = 0; i < NB * FILT; ++i) v[i] = 0.f;

        if (valid) {                     // wave-uniform (edge s skips one w)
            #pragma unroll
            for (int j = 0; j < 3; ++j) {
                const int kj = k0 + 64 * j;
                float wv[FILT];          // stride-24B LDS: 2-way alias, free
                #pragma unroll
                for (int o = 0; o < FILT; ++o) wv[o] = wlds[kj * FILT + o];

                float xv[NB];            // coalesced dwords, 8 in flight
                #pragma unroll
                for (int nb = 0; nb < NB; ++nb)
                    xv[nb] = xrow[(size_t)(b0 + nb) * (SEQ * FEAT) + 64 * j];

                #pragma unroll
                for (int nb = 0; nb < NB; ++nb)
                    #pragma unroll
                    for (int o = 0; o < FILT; ++o)
                        v[nb * FILT + o] = fmaf(xv[nb], wv[o], v[nb * FILT + o]);
            }
        }

        // In-wave halving tree: 48 partials -> lane<16 x 3 values
        #pragma unroll
        for (int step = 0; step < 4; ++step) {
            const int m    = 1 << step;
            const int half_ = 48 >> (step + 1);    // 24,12,6,3
            const bool upper = (lane & m) != 0;
            #pragma unroll
            for (int j = 0; j < half_; ++j) {
                float snd = upper ? v[j] : v[j + half_];
                float kep = upper ? v[j + half_] : v[j];
                v[j] = kep + __shfl_xor(snd, m, 64);
            }
        }
        #pragma unroll
        for (int j = 0; j < 3; ++j) {
            v[j] += __shfl_xor(v[j], 16, 64);
            v[j] += __shfl_xor(v[j], 32, 64);
        }

        // Cross-wave: write 48 partials per wave, single barrier (parity buf)
        float* rb = red[g & 1];
        if (lane < 16) {
            #pragma unroll
            for (int j = 0; j < 3; ++j)
                rb[wave * RSTR + 3 * gidx + j] = v[j];
        }
        __syncthreads();

        // Rotating finalizer wave sums 12 partials, bias+relu, store.
        const int ft = tid - ((g % NWAVES) << 6);
        if (ft >= 0 && ft < 48) {
            float sum = 0.f;
            #pragma unroll
            for (int vw = 0; vw < NWAVES; ++vw) sum += rb[vw * RSTR + ft];
            const int nb = ft / FILT;
            const int o  = ft - nb * FILT;
            float val = sum + bias[s * FILT + o];
            val = val > 0.f ? val : 0.f;
            out[((size_t)(b0 + nb) * SEQ + s) * FILT + o] = val;
        }
    }
}

extern "C" void kernel_launch(void* const* d_in, const int* in_sizes, int n_in,
                              void* d_out, int out_size, void* d_ws, size_t ws_size,
                              hipStream_t stream) {
    const float* x   = (const float*)d_in[0];  // (256, 256, 768) fp32
    const float* W   = (const float*)d_in[1];  // (256, 2304, 6) fp32
    const float* b   = (const float*)d_in[2];  // (256, 6) fp32
    float*       out = (float*)d_out;          // (256, 256, 6) fp32
    (void)in_sizes; (void)n_in; (void)out_size; (void)d_ws; (void)ws_size;
    pos_linear_kernel<<<SEQ * 2, BLOCK, 0, stream>>>(x, W, b, out);
}

// Round 2
// 336.656 us; speedup vs baseline: 1.1996x; 1.1996x over previous
//
#include <hip/hip_runtime.h>

#define SEQ   256
#define FEAT  768
#define FILT  6
#define WELEMS (2304 * FILT)       // 13824 floats per s

typedef __attribute__((ext_vector_type(8))) short s16x8;   // 8 bf16 (4 VGPRs)
typedef __attribute__((ext_vector_type(4))) float f32x4;   // MFMA C/D

// R7: MFMA rewrite. Per s: out[256b,6o] = win[256b,2304k] @ W[2304k,6o] via
// mfma_f32_16x16x32_bf16, 3-term hi/lo split (xh*wh + xh*wl + xl*wh; residual
// ~2^-16 rel). Kills the shuffle tree, the red[] buffer, the finalizer, and
// ALL per-group barriers (R5's 130us was lockstep overhead: every pipe <40%).
// Layout-agnosticism: A and B use the same internal (h,e)->k bijection, so
// loading A elem (h,e) from k=8h+e and B elem (h,e) from the same k is correct
// for ANY internal mapping; only C/D layout matters (HW-verified:
// col=lane&15, row=4*(lane>>4)+reg).
// Grid 512 = (s, batch-half): 2 blocks/CU (LDS 2x54KB<=160KB, ~70 VGPR<=128),
// 4 waves/SIMD free-running. Wave owns one 16-batch M-tile; 72 K-steps.
// B-frags prepacked in LDS (bf16 hi|lo) -> one ds_read_b128 per frag;
// A-frags = 8 consecutive floats of x -> 2 coalesced dwordx4 + in-reg cvt.
__global__ __launch_bounds__(512, 4)
void pos_linear_kernel(const float* __restrict__ x,
                       const float* __restrict__ W,
                       const float* __restrict__ bias,
                       float* __restrict__ out) {
    // hi frags [0,13824) shorts, lo frags [13824, 27648)
    // frag slot for k-step t, lane group h, col c: short idx (24t+6h+c)*8 + e
    __shared__ __align__(16) unsigned short wb[2 * 13824];

    const int blk   = blockIdx.x;
    const int halfb = blk >> 8;                     // batch half 0/1
    const int sb    = blk & 255;
    const int s     = ((sb & 7) << 5) | (sb >> 3);  // XCD-contiguous s ranges
    const int tid   = threadIdx.x;

    // ---- Stage W[s] -> bf16 hi/lo fragments in LDS (one-time) ----
    // thread owns k's; reads W[s][k][0..5] (coalesced dwords), truncating
    // split: hi = bits&0xffff0000, lo = bf16(f - hi). (k>>3)*6 == (4t+h)*6.
    {
        const float* Ws = W + (size_t)s * WELEMS;
        for (int k = tid; k < 2304; k += 512) {
            const int slot8 = (k >> 3) * 6;
            const int e     = k & 7;
            #pragma unroll
            for (int o = 0; o < FILT; ++o) {
                float f = Ws[k * FILT + o];
                unsigned int bi = __float_as_uint(f);
                float rem = f - __uint_as_float(bi & 0xffff0000u);
                wb[(slot8 + o) * 8 + e]         = (unsigned short)(bi >> 16);
                wb[13824 + (slot8 + o) * 8 + e] =
                    (unsigned short)(__float_as_uint(rem) >> 16);
            }
        }
    }
    __syncthreads();   // the ONLY barrier; waves free-run from here

    const int lane = tid & 63;
    const int wave = tid >> 6;        // 0..7
    const int row  = lane & 15;       // batch within M-tile (A side)
    const int h    = lane >> 4;       // k-group 0..3
    const int col  = lane & 15;       // output col (valid < 6, B side)
    const bool cv  = col < FILT;
    const int b0   = (halfb << 7) + (wave << 4);      // tile batch base

    const int bidx = (6 * h + col) * 8;               // B-frag short base
    const s16x8 z8 = {0, 0, 0, 0, 0, 0, 0, 0};

    f32x4 acc_hh = {0, 0, 0, 0};
    f32x4 acc_hl = {0, 0, 0, 0};
    f32x4 acc_lh = {0, 0, 0, 0};

    // per-lane x base: batch (b0+row), feature offset 8h; band adds r*FEAT
    const float* xb = x + (size_t)(b0 + row) * (SEQ * FEAT) + 8 * h;

    // one MFMA K-step: convert 8 floats -> hi/lo bf16 frags, read B, 3 MFMA
    auto step = [&](f32x4 u, f32x4 v, int tg) {
        s16x8 ah, al;
        #pragma unroll
        for (int e = 0; e < 8; ++e) {
            float f = (e < 4) ? u[e] : v[e - 4];
            unsigned int bi = __float_as_uint(f);
            ah[e] = (short)(bi >> 16);
            float rem = f - __uint_as_float(bi & 0xffff0000u);
            al[e] = (short)(__float_as_uint(rem) >> 16);
        }
        // lanes col>=6: B column is zero (D cols 6..15 unused). A data from
        // ALL 64 lanes is real x (required: every lane supplies A rows).
        s16x8 bh = cv ? *(const s16x8*)&wb[bidx + 192 * tg]         : z8;
        s16x8 bl = cv ? *(const s16x8*)&wb[13824 + bidx + 192 * tg] : z8;
        acc_hh = __builtin_amdgcn_mfma_f32_16x16x32_bf16(ah, bh, acc_hh, 0, 0, 0);
        acc_hl = __builtin_amdgcn_mfma_f32_16x16x32_bf16(ah, bl, acc_hl, 0, 0, 0);
        acc_lh = __builtin_amdgcn_mfma_f32_16x16x32_bf16(al, bh, acc_lh, 0, 0, 0);
    };

    // 3 window bands; within band w, K-step t24: f = 32*t24 + 8h + e,
    // global t = 24w + t24. Band skip at s=0 / s=255 == zero padding.
    #pragma unroll
    for (int w = 0; w < 3; ++w) {
        const int r = s - 1 + w;
        if (r < 0 || r >= SEQ) continue;              // block-uniform
        const f32x4* ap = (const f32x4*)(xb + (size_t)r * FEAT);
        const int tb = 24 * w;

        // depth-2 A prefetch: load t+2 while converting/MFMA'ing t
        f32x4 cu = ap[0], cw = ap[1];                 // t24 = 0
        f32x4 nu = ap[8], nw = ap[9];                 // t24 = 1
        #pragma unroll 2
        for (int t = 0; t < 22; ++t) {
            f32x4 fu = cu, fv = cw;
            cu = nu; cw = nw;
            nu = ap[8 * t + 16];                      // t24 = t + 2
            nw = ap[8 * t + 17];
            step(fu, fv, tb + t);
        }
        step(cu, cw, tb + 22);
        step(nu, nw, tb + 23);
    }

    // C/D: col = lane&15, row = 4*(lane>>4) + reg  [HW-verified mapping]
    if (cv) {
        const float bv = bias[s * FILT + col];
        #pragma unroll
        for (int g = 0; g < 4; ++g) {
            const int b = b0 + 4 * h + g;
            float vsum = acc_hh[g] + acc_hl[g] + acc_lh[g] + bv;
            vsum = vsum > 0.f ? vsum : 0.f;
            out[((size_t)b * SEQ + s) * FILT + col] = vsum;
        }
    }
}

extern "C" void kernel_launch(void* const* d_in, const int* in_sizes, int n_in,
                              void* d_out, int out_size, void* d_ws, size_t ws_size,
                              hipStream_t stream) {
    const float* x   = (const float*)d_in[0];  // (256, 256, 768) fp32
    const float* W   = (const float*)d_in[1];  // (256, 2304, 6) fp32
    const float* b   = (const float*)d_in[2];  // (256, 6) fp32
    float*       out = (float*)d_out;          // (256, 256, 6) fp32
    (void)in_sizes; (void)n_in; (void)out_size; (void)d_ws; (void)ws_size;
    pos_linear_kernel<<<SEQ * 2, 512, 0, stream>>>(x, W, b, out);
}

// Round 3
// 295.208 us; speedup vs baseline: 1.3680x; 1.1404x over previous
//
#include <hip/hip_runtime.h>

#define SEQ   256
#define FEAT  768
#define FILT  6
#define WELEMS (2304 * FILT)       // 13824 floats per s

typedef __attribute__((ext_vector_type(8))) short s16x8;   // 8 bf16 (4 VGPRs)
typedef __attribute__((ext_vector_type(4))) float f32x4;   // MFMA C/D

// R8: mod-3 band phasing. R7's 137us == 604MB logical L2-miss / 4.4 TB/s
// fill: the 3 blocks s-1,s,s+1 that share row r read it in different band
// phases (1/3 kernel apart) -> zero L2 reuse. Now block s processes band
// w = (p - s + 256) % 3 in phase p, so row r is read by ALL its consumers
// in phase p = r mod 3, same wave->batch map, same K order -> 2 of 3 reads
// become L2 hits; logical misses ~604 -> ~215 MB. __syncthreads between
// phases (3 barriers, not R5's 32) keeps waves aligned. Prefetch depth
// 2 -> 4 K-steps (8 dwordx4 in flight/wave) covers residual miss latency.
// Rest identical to R7: per s, out[256b,6o] = win[256b,2304k] @ W[2304k,6o]
// via mfma_f32_16x16x32_bf16, 3-term hi/lo split; B-frags prepacked in LDS
// (hi|lo bf16); C/D layout col=lane&15, row=4*(lane>>4)+reg (HW-verified).
__global__ __launch_bounds__(512, 4)
void pos_linear_kernel(const float* __restrict__ x,
                       const float* __restrict__ W,
                       const float* __restrict__ bias,
                       float* __restrict__ out) {
    // hi frags [0,13824) shorts, lo frags [13824, 27648)
    // frag slot for k-step t, lane group h, col c: short idx (24t+6h+c)*8 + e
    __shared__ __align__(16) unsigned short wb[2 * 13824];

    const int blk   = blockIdx.x;
    const int halfb = blk >> 8;                     // batch half 0/1
    const int sb    = blk & 255;
    const int s     = ((sb & 7) << 5) | (sb >> 3);  // XCD-contiguous s ranges
    const int tid   = threadIdx.x;

    // ---- Stage W[s] -> bf16 hi/lo fragments in LDS (one-time) ----
    {
        const float* Ws = W + (size_t)s * WELEMS;
        for (int k = tid; k < 2304; k += 512) {
            const int slot8 = (k >> 3) * 6;
            const int e     = k & 7;
            #pragma unroll
            for (int o = 0; o < FILT; ++o) {
                float f = Ws[k * FILT + o];
                unsigned int bi = __float_as_uint(f);
                float rem = f - __uint_as_float(bi & 0xffff0000u);
                wb[(slot8 + o) * 8 + e]         = (unsigned short)(bi >> 16);
                wb[13824 + (slot8 + o) * 8 + e] =
                    (unsigned short)(__float_as_uint(rem) >> 16);
            }
        }
    }
    __syncthreads();

    const int lane = tid & 63;
    const int wave = tid >> 6;        // 0..7
    const int row  = lane & 15;       // batch within M-tile (A side)
    const int h    = lane >> 4;       // k-group 0..3
    const int col  = lane & 15;       // output col (valid < 6, B side)
    const bool cv  = col < FILT;
    const int b0   = (halfb << 7) + (wave << 4);      // tile batch base

    const int bidx = (6 * h + col) * 8;               // B-frag short base
    const s16x8 z8 = {0, 0, 0, 0, 0, 0, 0, 0};

    f32x4 acc_hh = {0, 0, 0, 0};
    f32x4 acc_hl = {0, 0, 0, 0};
    f32x4 acc_lh = {0, 0, 0, 0};

    // per-lane x base: batch (b0+row), feature offset 8h; band adds r*FEAT
    const float* xb = x + (size_t)(b0 + row) * (SEQ * FEAT) + 8 * h;

    // one MFMA K-step: convert 8 floats -> hi/lo bf16 frags, read B, 3 MFMA
    auto step = [&](f32x4 u, f32x4 v, int tg) {
        s16x8 ah, al;
        #pragma unroll
        for (int e = 0; e < 8; ++e) {
            float f = (e < 4) ? u[e] : v[e - 4];
            unsigned int bi = __float_as_uint(f);
            ah[e] = (short)(bi >> 16);
            float rem = f - __uint_as_float(bi & 0xffff0000u);
            al[e] = (short)(__float_as_uint(rem) >> 16);
        }
        // lanes col>=6: B column is zero (D cols 6..15 unused); A from all
        // 64 lanes is real x (every lane supplies A rows).
        s16x8 bh = cv ? *(const s16x8*)&wb[bidx + 192 * tg]         : z8;
        s16x8 bl = cv ? *(const s16x8*)&wb[13824 + bidx + 192 * tg] : z8;
        acc_hh = __builtin_amdgcn_mfma_f32_16x16x32_bf16(ah, bh, acc_hh, 0, 0, 0);
        acc_hl = __builtin_amdgcn_mfma_f32_16x16x32_bf16(ah, bl, acc_hl, 0, 0, 0);
        acc_lh = __builtin_amdgcn_mfma_f32_16x16x32_bf16(al, bh, acc_lh, 0, 0, 0);
    };

    // 3 phases; in phase p process the band whose row r = s-1+w satisfies
    // r % 3 == p  (w = (p - (s-1)) mod 3; +255 keeps the arg positive,
    // 255 % 3 == 0). Band skip at s=0 / s=255 == zero padding.
    #pragma unroll
    for (int p = 0; p < 3; ++p) {
        const int w = (p - s + 256) % 3;              // (p-(s-1)+255) % 3
        const int r = s - 1 + w;
        if (r >= 0 && r < SEQ) {                      // block-uniform
            const f32x4* ap = (const f32x4*)(xb + (size_t)r * FEAT);
            const int tb = 24 * w;

            // depth-4 circular prefetch: 8 dwordx4 in flight per wave
            f32x4 qa[4], qb[4];
            #pragma unroll
            for (int t = 0; t < 4; ++t) { qa[t] = ap[8 * t]; qb[t] = ap[8 * t + 1]; }
            #pragma unroll
            for (int t = 0; t < 24; ++t) {            // full unroll: t&3 static
                f32x4 u = qa[t & 3], v = qb[t & 3];
                if (t + 4 < 24) {
                    qa[t & 3] = ap[8 * (t + 4)];
                    qb[t & 3] = ap[8 * (t + 4) + 1];
                }
                step(u, v, tb + t);
            }
        }
        __syncthreads();   // phase alignment: keep all consumers of row r
    }                      // temporally coincident (L2 residency ~ few us)

    // C/D: col = lane&15, row = 4*(lane>>4) + reg  [HW-verified mapping]
    if (cv) {
        const float bv = bias[s * FILT + col];
        #pragma unroll
        for (int g = 0; g < 4; ++g) {
            const int b = b0 + 4 * h + g;
            float vsum = acc_hh[g] + acc_hl[g] + acc_lh[g] + bv;
            vsum = vsum > 0.f ? vsum : 0.f;
            out[((size_t)b * SEQ + s) * FILT + col] = vsum;
        }
    }
}

extern "C" void kernel_launch(void* const* d_in, const int* in_sizes, int n_in,
                              void* d_out, int out_size, void* d_ws, size_t ws_size,
                              hipStream_t stream) {
    const float* x   = (const float*)d_in[0];  // (256, 256, 768) fp32
    const float* W   = (const float*)d_in[1];  // (256, 2304, 6) fp32
    const float* b   = (const float*)d_in[2];  // (256, 6) fp32
    float*       out = (float*)d_out;          // (256, 256, 6) fp32
    (void)in_sizes; (void)n_in; (void)out_size; (void)d_ws; (void)ws_size;
    pos_linear_kernel<<<SEQ * 2, 512, 0, stream>>>(x, W, b, out);
}